// Round 1
// baseline (277.645 us; speedup 1.0000x reference)
//
#include <hip/hip_runtime.h>
#include <cmath>

#define NBATCH 8
#define NCH    256
#define NH     80
#define NW     160
#define NDISP  24
#define FAC    8

constexpr int SLAB  = 8;
constexpr int NSLAB = NCH / SLAB;
constexpr int APR   = 24;              // zero apron so R[w-i] reads are always in-bounds (+0.0f adds are exact)
constexpr int RWP   = APR + NW;        // 184

// ---------------- K1: cost volume (sequential-c, no-FMA) + top3 + softmax expectation ----------------
__global__ __launch_bounds__(NW) void cost_topk_kernel(
    const float* __restrict__ left, const float* __restrict__ right,
    float* __restrict__ disp)
{
#pragma clang fp contract(off)
  __shared__ float Ls[SLAB][NW];
  __shared__ float Rs[SLAB][RWP];

  const int t = threadIdx.x;           // 0..159  (thread = one w column)
  const int b = blockIdx.x / NH;
  const int h = blockIdx.x % NH;
  const int w = t;

  // zero the R apron once (192 words)
  for (int q = t; q < SLAB * APR; q += NW)
    Rs[q / APR][q % APR] = 0.0f;

  float acc[NDISP];
#pragma unroll
  for (int i = 0; i < NDISP; ++i) acc[i] = 0.0f;

  const size_t chanStride = (size_t)NH * NW;
  const float* lrow = left  + (size_t)b * NCH * chanStride + (size_t)h * NW;
  const float* rrow = right + (size_t)b * NCH * chanStride + (size_t)h * NW;

  float4 pl[2], pr[2];
  // prefetch slab 0
#pragma unroll
  for (int k = 0; k < 2; ++k) {
    int e  = (k * NW + t) * 4;         // 0..1276, multiple of 4
    int cc = e / NW;
    int x  = e - cc * NW;
    size_t off = (size_t)cc * chanStride + x;
    pl[k] = *reinterpret_cast<const float4*>(lrow + off);
    pr[k] = *reinterpret_cast<const float4*>(rrow + off);
  }

  for (int s = 0; s < NSLAB; ++s) {
    __syncthreads();                   // previous compute done (and apron init on s==0)
    // write staged slab s to LDS
#pragma unroll
    for (int k = 0; k < 2; ++k) {
      int e  = (k * NW + t) * 4;
      int cc = e / NW;
      int x  = e - cc * NW;
      *reinterpret_cast<float4*>(&Ls[cc][x])       = pl[k];
      *reinterpret_cast<float4*>(&Rs[cc][APR + x]) = pr[k];
    }
    // issue global loads for slab s+1 (latency hides under compute)
    if (s + 1 < NSLAB) {
      const int c0 = (s + 1) * SLAB;
#pragma unroll
      for (int k = 0; k < 2; ++k) {
        int e  = (k * NW + t) * 4;
        int cc = e / NW;
        int x  = e - cc * NW;
        size_t off = (size_t)(c0 + cc) * chanStride + x;
        pl[k] = *reinterpret_cast<const float4*>(lrow + off);
        pr[k] = *reinterpret_cast<const float4*>(rrow + off);
      }
    }
    __syncthreads();
    // sequential accumulation over channels, strictly ascending c, mul then add (no FMA)
#pragma unroll
    for (int cc = 0; cc < SLAB; ++cc) {
      float lv = Ls[cc][w];
      const float* rp = &Rs[cc][APR + w];
#pragma unroll
      for (int i = 0; i < NDISP; ++i)
        acc[i] = acc[i] + lv * rp[-i];
    }
  }

  // mean (exact scale by 2^-8)
#pragma unroll
  for (int i = 0; i < NDISP; ++i) acc[i] *= 0.00390625f;

  // top-3 scan; strict > keeps lower index on ties (matches lax.top_k)
  float v1 = -1e30f, v2 = -1e30f, v3 = -1e30f;
  int   j1 = 0, j2 = 0, j3 = 0;
#pragma unroll
  for (int i = 0; i < NDISP; ++i) {
    float v = acc[i];
    if (v > v1)      { v3 = v2; j3 = j2; v2 = v1; j2 = j1; v1 = v; j1 = i; }
    else if (v > v2) { v3 = v2; j3 = j2; v2 = v;  j2 = i; }
    else if (v > v3) { v3 = v;  j3 = i; }
  }
  float e2 = expf(v2 - v1), e3 = expf(v3 - v1);
  float ssum = 1.0f + e2 + e3;
  float dv = ((float)j1 + e2 * (float)j2 + e3 * (float)j3) / ssum;
  disp[((size_t)b * NH + h) * NW + w] = dv;
}

// ---------------- K2: mask-softmax convex upsample, one thread per coarse pixel ----------------
__global__ __launch_bounds__(256) void upsample_kernel(
    const float* __restrict__ disp, const float* __restrict__ mask,
    const int* __restrict__ itp, float* __restrict__ out)
{
  int idx = blockIdx.x * 256 + threadIdx.x;
  if (idx >= NBATCH * NH * NW) return;
  const int w = idx % NW;
  const int h = (idx / NW) % NH;
  const int b = idx / (NH * NW);

  const float iters = (float)itp[0];
  const float temp  = 1.0f + expf(-(iters - 1.0f));
  const float invt  = 1.0f / temp;

  // 3x3 disparity neighborhood (zero-padded), j = dy*3+dx row-major like F.unfold
  float d[9];
#pragma unroll
  for (int dy = 0; dy < 3; ++dy)
#pragma unroll
    for (int dx = 0; dx < 3; ++dx) {
      int hh = h + dy - 1, ww = w + dx - 1;
      bool ok = (hh >= 0) && (hh < NH) && (ww >= 0) && (ww < NW);
      d[dy * 3 + dx] = ok ? disp[((size_t)b * NH + hh) * NW + ww] : 0.0f;
    }

  const size_t hw = (size_t)NH * NW;
  const float* mb = mask + (size_t)b * 576 * hw + (size_t)h * NW + w;
  float* ob = out + (size_t)b * (8 * NH) * (8 * NW);

  for (int fy = 0; fy < FAC; ++fy) {
    for (int fx = 0; fx < FAC; ++fx) {
      float m[9];
#pragma unroll
      for (int j = 0; j < 9; ++j)
        m[j] = mb[(size_t)(j * 64 + fy * 8 + fx) * hw];
      float mx = m[0];
#pragma unroll
      for (int j = 1; j < 9; ++j) mx = fmaxf(mx, m[j]);
      float ssum = 0.0f, accv = 0.0f;
#pragma unroll
      for (int j = 0; j < 9; ++j) {
        float e = expf((m[j] - mx) * invt);
        ssum += e;
        accv += e * d[j];
      }
      ob[(size_t)(8 * h + fy) * (8 * NW) + (8 * w + fx)] = -8.0f * accv / ssum;
    }
  }
}

extern "C" void kernel_launch(void* const* d_in, const int* in_sizes, int n_in,
                              void* d_out, int out_size, void* d_ws, size_t ws_size,
                              hipStream_t stream) {
  (void)in_sizes; (void)n_in; (void)out_size; (void)ws_size;
  const float* left  = (const float*)d_in[0];
  const float* right = (const float*)d_in[1];
  const float* mask  = (const float*)d_in[2];
  const int*   iters = (const int*)d_in[3];
  float* out  = (float*)d_out;
  float* disp = (float*)d_ws;   // 8*80*160 f32 = 409,600 B scratch

  hipLaunchKernelGGL(cost_topk_kernel, dim3(NBATCH * NH), dim3(NW), 0, stream,
                     left, right, disp);
  hipLaunchKernelGGL(upsample_kernel, dim3((NBATCH * NH * NW + 255) / 256), dim3(256), 0, stream,
                     disp, mask, iters, out);
}

// Round 2
// 156.703 us; speedup vs baseline: 1.7718x; 1.7718x over previous
//
#include <hip/hip_runtime.h>
#include <cmath>

#define NBATCH 8
#define NCH    256
#define NH     80
#define NW     160
#define NDISP  24
#define FAC    8

constexpr int CG   = 8;         // channel groups per block
constexpr int CPG  = NCH / CG;  // 32 sequential channels per thread
constexpr int WQ   = NW / 4;    // 40 w-quads
constexpr int TPB  = WQ * CG;   // 320 threads = 5 waves
constexpr int ROWF = 348;       // padded floats per staged channel row: 160 L | 24 apron | 160 R | 4 pad
constexpr int BUFF = CG * ROWF; // 2784 floats per stage buffer
constexpr int PSTR = 644;       // partial-reduce stride per cg (4*160 + 4 pad)

__device__ __forceinline__ float f4c(const float4& v, int k) {
  switch (k) { case 0: return v.x; case 1: return v.y; case 2: return v.z; default: return v.w; }
}

// ---------------- K1: cost volume + top3 + softmax expectation ----------------
// block = one (b,h) row; thread = (cg = t&7, wq = t>>3); 96 accumulators/thread.
__global__ __launch_bounds__(TPB) void cost_topk_kernel(
    const float* __restrict__ left, const float* __restrict__ right,
    float* __restrict__ disp)
{
#pragma clang fp contract(off)
  // union: phase1 stage[2][8][348] = 5568 f;  phase2 P[8*644]=5152 f + C[24*160]=3840 f
  __shared__ float smem[9000];

  const int t  = threadIdx.x;
  const int cg = t & 7;
  const int wq = t >> 3;
  const int w0 = wq * 4;
  const int b  = blockIdx.x / NH;
  const int h  = blockIdx.x % NH;

  const size_t hw = (size_t)NH * NW;
  const float* lrow = left  + (size_t)b * NCH * hw + (size_t)h * NW;
  const float* rrow = right + (size_t)b * NCH * hw + (size_t)h * NW;

  // zero the 24-float R aprons of both stage buffers (96 quads)
  for (int q = t; q < 2 * CG * 6; q += TPB) {
    int buf = q / 48, ch = (q / 6) % 8, k = q % 6;
    *reinterpret_cast<float4*>(&smem[buf * BUFF + ch * ROWF + 160 + 4 * k]) = float4{0.f, 0.f, 0.f, 0.f};
  }

  // staging assignment: this thread owns global quads qA=t, qB=t+TPB of 640 (8ch x (40 L + 40 R) quads)
  const int qa = t, qb = t + TPB;
  const int chA = qa / 80, remA = qa % 80;
  const int chB = qb / 80, remB = qb % 80;
  const int ldsA = chA * ROWF + ((remA < 40) ? remA * 4 : 184 + (remA - 40) * 4);
  const int ldsB = chB * ROWF + ((remB < 40) ? remB * 4 : 184 + (remB - 40) * 4);
  const float* gA = ((remA < 40) ? lrow : rrow) + (size_t)chA * CPG * hw + ((remA < 40) ? remA * 4 : (remA - 40) * 4);
  const float* gB = ((remB < 40) ? lrow : rrow) + (size_t)chB * CPG * hw + ((remB < 40) ? remB * 4 : (remB - 40) * 4);

  float4 s0 = *reinterpret_cast<const float4*>(gA);
  float4 s1 = *reinterpret_cast<const float4*>(gB);

  float acc[NDISP][4];
#pragma unroll
  for (int i = 0; i < NDISP; ++i)
#pragma unroll
    for (int ws = 0; ws < 4; ++ws) acc[i][ws] = 0.f;

  for (int j = 0; j < CPG; ++j) {
    float* base = &smem[(j & 1) * BUFF];
    __syncthreads();                                 // prior compute on this buffer done (+apron init)
    *reinterpret_cast<float4*>(&base[ldsA]) = s0;
    *reinterpret_cast<float4*>(&base[ldsB]) = s1;
    if (j + 1 < CPG) {                               // prefetch next channel set
      s0 = *reinterpret_cast<const float4*>(gA + (size_t)(j + 1) * hw);
      s1 = *reinterpret_cast<const float4*>(gB + (size_t)(j + 1) * hw);
    }
    __syncthreads();

    const float* row = base + cg * ROWF;             // this thread's channel c = cg*32 + j
    float4 L  = *reinterpret_cast<const float4*>(row + w0);
    float4 Qa = *reinterpret_cast<const float4*>(row + 160 + w0);       // R[x=w0-24..w0-21]
#pragma unroll
    for (int g = 0; g < 6; ++g) {
      const int i0 = 20 - 4 * g;
      float4 Qb = *reinterpret_cast<const float4*>(row + 184 + w0 - i0); // R[x=w0-i0..]
#pragma unroll
      for (int di = 0; di < 4; ++di)
#pragma unroll
        for (int ws = 0; ws < 4; ++ws) {
          const int pos = ws - di + 4;               // 1..7 within [Qa|Qb]
          float rv = (pos < 4) ? f4c(Qa, pos) : f4c(Qb, pos - 4);
          acc[i0 + di][ws] = acc[i0 + di][ws] + f4c(L, ws) * rv;        // mul+add, no FMA
        }
      Qa = Qb;
    }
  }

  // -------- reduce 8 channel-group partials, then top-3 --------
  float* P = smem;            // 8*644 floats
  float* C = smem + 5160;     // 24*160 floats
#pragma unroll
  for (int ic = 0; ic < 6; ++ic) {
    __syncthreads();          // previous chunk's P fully consumed / compute done
#pragma unroll
    for (int ip = 0; ip < 4; ++ip)
      *reinterpret_cast<float4*>(&P[cg * PSTR + ip * 160 + w0]) =
          float4{acc[ic * 4 + ip][0], acc[ic * 4 + ip][1], acc[ic * 4 + ip][2], acc[ic * 4 + ip][3]};
    __syncthreads();
#pragma unroll
    for (int r = 0; r < 2; ++r) {
      int p = t + r * TPB;    // 0..639
      int ip = p / 160, w = p % 160;
      float s = 0.f;
#pragma unroll
      for (int g = 0; g < 8; ++g) s = s + P[g * PSTR + ip * 160 + w];   // ascending cg order
      C[(ic * 4 + ip) * 160 + w] = s * 0.00390625f;  // mean: exact *2^-8
    }
  }
  __syncthreads();

  if (t < NW) {
    float v1 = -1e30f, v2 = -1e30f, v3 = -1e30f;
    int   j1 = 0, j2 = 0, j3 = 0;
#pragma unroll
    for (int i = 0; i < NDISP; ++i) {
      float v = C[i * 160 + t];
      if (v > v1)      { v3 = v2; j3 = j2; v2 = v1; j2 = j1; v1 = v; j1 = i; }
      else if (v > v2) { v3 = v2; j3 = j2; v2 = v;  j2 = i; }
      else if (v > v3) { v3 = v;  j3 = i; }
    }
    float e2 = expf(v2 - v1), e3 = expf(v3 - v1);
    float ssum = 1.0f + e2 + e3;
    float dv = ((float)j1 + e2 * (float)j2 + e3 * (float)j3) / ssum;
    disp[((size_t)b * NH + h) * NW + t] = dv;
  }
}

// ---------------- K2: convex upsample, one thread per OUTPUT pixel ----------------
__global__ __launch_bounds__(256) void upsample_kernel(
    const float* __restrict__ disp, const float* __restrict__ mask,
    const int* __restrict__ itp, float* __restrict__ out)
{
  const int WW = NW * FAC, HH = NH * FAC;
  int idx = blockIdx.x * 256 + threadIdx.x;          // 8*640*1280 = 6,553,600 exactly
  int ww = idx % WW;
  int hh = (idx / WW) % HH;
  int b  = idx / (WW * HH);
  int w = ww >> 3, fx = ww & 7;
  int h = hh >> 3, fy = hh & 7;

  float iters = (float)itp[0];
  float temp  = 1.0f + __expf(-(iters - 1.0f));
  float sc    = 1.44269504088896340736f / temp;      // log2(e)/temp

  const size_t hw = (size_t)NH * NW;
  const float* drow = disp + (size_t)b * hw;
  float d[9];
#pragma unroll
  for (int dy = 0; dy < 3; ++dy)
#pragma unroll
    for (int dx = 0; dx < 3; ++dx) {
      int h2 = h + dy - 1, w2 = w + dx - 1;
      bool ok = (h2 >= 0) && (h2 < NH) && (w2 >= 0) && (w2 < NW);
      d[dy * 3 + dx] = ok ? drow[h2 * NW + w2] : 0.f;
    }

  const float* mb = mask + ((size_t)b * 576 + (size_t)(fy * 8 + fx)) * hw + (size_t)h * NW + w;
  float m[9];
#pragma unroll
  for (int j = 0; j < 9; ++j) m[j] = mb[(size_t)j * 64 * hw];
  float mx = m[0];
#pragma unroll
  for (int j = 1; j < 9; ++j) mx = fmaxf(mx, m[j]);
  float ssum = 0.f, accv = 0.f;
#pragma unroll
  for (int j = 0; j < 9; ++j) {
    float e = exp2f((m[j] - mx) * sc);
    ssum += e;
    accv += e * d[j];
  }
  out[idx] = -8.0f * accv / ssum;
}

extern "C" void kernel_launch(void* const* d_in, const int* in_sizes, int n_in,
                              void* d_out, int out_size, void* d_ws, size_t ws_size,
                              hipStream_t stream) {
  (void)in_sizes; (void)n_in; (void)out_size; (void)ws_size;
  const float* left  = (const float*)d_in[0];
  const float* right = (const float*)d_in[1];
  const float* mask  = (const float*)d_in[2];
  const int*   iters = (const int*)d_in[3];
  float* out  = (float*)d_out;
  float* disp = (float*)d_ws;   // 8*80*160 f32 scratch

  hipLaunchKernelGGL(cost_topk_kernel, dim3(NBATCH * NH), dim3(TPB), 0, stream,
                     left, right, disp);
  hipLaunchKernelGGL(upsample_kernel, dim3(NBATCH * NH * NW * FAC * FAC / 256), dim3(256), 0, stream,
                     disp, mask, iters, out);
}

// Round 3
// 152.470 us; speedup vs baseline: 1.8210x; 1.0278x over previous
//
#include <hip/hip_runtime.h>
#include <cmath>

#define NBATCH 8
#define NCH    256
#define NH     80
#define NW     160
#define NDISP  24
#define FAC    8

constexpr int CG   = 8;         // channel groups per block (reduced via shfl butterfly)
constexpr int CPG  = NCH / CG;  // 32 sequential channels per thread
constexpr int WQ   = NW / 4;    // 40 w-quads
constexpr int TPB  = WQ * CG;   // 320 threads = 5 waves
constexpr int ROWF = 348;       // padded floats per staged channel row: 160 L | 24 apron | 160 R | 4 pad
constexpr int BUFF = CG * ROWF; // 2784 floats per stage buffer

__device__ __forceinline__ float f4c(const float4& v, int k) {
  switch (k) { case 0: return v.x; case 1: return v.y; case 2: return v.z; default: return v.w; }
}

// ---------------- K1: cost volume + in-register reduce + top3 + softmax expectation ----------------
// block = one (b,h) row; thread = (cg = t&7, wq = t>>3); 96 accumulators/thread.
// The 8 cg-partials for a given wq sit in 8 consecutive lanes -> 3-step shfl_xor butterfly.
__global__ __launch_bounds__(TPB) void cost_topk_kernel(
    const float* __restrict__ left, const float* __restrict__ right,
    float* __restrict__ disp)
{
  __shared__ float smem[2 * BUFF];     // 22272 B

  const int t  = threadIdx.x;
  const int cg = t & 7;
  const int wq = t >> 3;
  const int w0 = wq * 4;
  const int b  = blockIdx.x / NH;
  const int h  = blockIdx.x % NH;

  const size_t hw = (size_t)NH * NW;
  const float* lrow = left  + (size_t)b * NCH * hw + (size_t)h * NW;
  const float* rrow = right + (size_t)b * NCH * hw + (size_t)h * NW;

  // zero the 24-float R aprons of both stage buffers
  for (int q = t; q < 2 * CG * 6; q += TPB) {
    int buf = q / 48, ch = (q / 6) % 8, k = q % 6;
    *reinterpret_cast<float4*>(&smem[buf * BUFF + ch * ROWF + 160 + 4 * k]) = float4{0.f, 0.f, 0.f, 0.f};
  }

  // staging: this thread owns global quads qa=t, qb=t+TPB of 640 (8ch x (40 L + 40 R) quads)
  const int qa = t, qb = t + TPB;
  const int chA = qa / 80, remA = qa % 80;
  const int chB = qb / 80, remB = qb % 80;
  const int ldsA = chA * ROWF + ((remA < 40) ? remA * 4 : 184 + (remA - 40) * 4);
  const int ldsB = chB * ROWF + ((remB < 40) ? remB * 4 : 184 + (remB - 40) * 4);
  const float* gA = ((remA < 40) ? lrow : rrow) + (size_t)chA * CPG * hw + ((remA < 40) ? remA * 4 : (remA - 40) * 4);
  const float* gB = ((remB < 40) ? lrow : rrow) + (size_t)chB * CPG * hw + ((remB < 40) ? remB * 4 : (remB - 40) * 4);

  float4 s0 = *reinterpret_cast<const float4*>(gA);
  float4 s1 = *reinterpret_cast<const float4*>(gB);

  float acc[NDISP][4];
#pragma unroll
  for (int i = 0; i < NDISP; ++i)
#pragma unroll
    for (int ws = 0; ws < 4; ++ws) acc[i][ws] = 0.f;

  for (int j = 0; j < CPG; ++j) {
    float* base = &smem[(j & 1) * BUFF];
    __syncthreads();                                 // prior compute on this buffer done (+apron init)
    *reinterpret_cast<float4*>(&base[ldsA]) = s0;
    *reinterpret_cast<float4*>(&base[ldsB]) = s1;
    if (j + 1 < CPG) {                               // prefetch next channel set
      s0 = *reinterpret_cast<const float4*>(gA + (size_t)(j + 1) * hw);
      s1 = *reinterpret_cast<const float4*>(gB + (size_t)(j + 1) * hw);
    }
    __syncthreads();

    const float* row = base + cg * ROWF;             // this thread's channel c = cg*32 + j
    float4 L  = *reinterpret_cast<const float4*>(row + w0);
    float4 Qa = *reinterpret_cast<const float4*>(row + 160 + w0);        // R[x=w0-24..w0-21]
#pragma unroll
    for (int g = 0; g < 6; ++g) {
      const int i0 = 20 - 4 * g;
      float4 Qb = *reinterpret_cast<const float4*>(row + 184 + w0 - i0); // R[x=w0-i0..]
#pragma unroll
      for (int di = 0; di < 4; ++di)
#pragma unroll
        for (int ws = 0; ws < 4; ++ws) {
          const int pos = ws - di + 4;               // 1..7 within [Qa|Qb]
          float rv = (pos < 4) ? f4c(Qa, pos) : f4c(Qb, pos - 4);
          acc[i0 + di][ws] = __builtin_fmaf(f4c(L, ws), rv, acc[i0 + di][ws]);
        }
      Qa = Qb;
    }
  }

  // -------- butterfly reduce over the 8 cg lanes (deterministic symmetric tree) --------
#pragma unroll
  for (int mskm = 1; mskm < 8; mskm <<= 1)
#pragma unroll
    for (int i = 0; i < NDISP; ++i)
#pragma unroll
      for (int ws = 0; ws < 4; ++ws)
        acc[i][ws] += __shfl_xor(acc[i][ws], mskm, 64);

  if (cg == 0) {
    float o[4];
#pragma unroll
    for (int ws = 0; ws < 4; ++ws) {
      float v1 = -1e30f, v2 = -1e30f, v3 = -1e30f;
      int   j1 = 0, j2 = 0, j3 = 0;
#pragma unroll
      for (int i = 0; i < NDISP; ++i) {
        float v = acc[i][ws] * 0.00390625f;          // mean: exact *2^-8
        if (v > v1)      { v3 = v2; j3 = j2; v2 = v1; j2 = j1; v1 = v; j1 = i; }
        else if (v > v2) { v3 = v2; j3 = j2; v2 = v;  j2 = i; }
        else if (v > v3) { v3 = v;  j3 = i; }
      }
      float e2 = expf(v2 - v1), e3 = expf(v3 - v1);
      float ssum = 1.0f + e2 + e3;
      o[ws] = ((float)j1 + e2 * (float)j2 + e3 * (float)j3) / ssum;
    }
    *reinterpret_cast<float4*>(&disp[((size_t)b * NH + h) * NW + w0]) = float4{o[0], o[1], o[2], o[3]};
  }
}

// ---------------- K2: convex upsample, one thread per (b,h,fy,w) -> 8 fx outputs ----------------
__global__ __launch_bounds__(256) void upsample_kernel(
    const float* __restrict__ disp, const float* __restrict__ mask,
    const int* __restrict__ itp, float* __restrict__ out)
{
  int idx = blockIdx.x * 256 + threadIdx.x;          // 8*80*8*160 = 819,200 exactly
  const int w  = idx % NW;
  const int fy = (idx / NW) & 7;
  const int h  = (idx / (NW * FAC)) % NH;
  const int b  = idx / (NW * FAC * NH);

  const float iters = (float)itp[0];
  const float temp  = 1.0f + __expf(-(iters - 1.0f));
  const float sc    = 1.44269504088896340736f / temp;  // log2(e)/temp

  const size_t hw = (size_t)NH * NW;
  const float* drow = disp + (size_t)b * hw;
  float d[9];
#pragma unroll
  for (int dy = 0; dy < 3; ++dy)
#pragma unroll
    for (int dx = 0; dx < 3; ++dx) {
      int h2 = h + dy - 1, w2 = w + dx - 1;
      bool ok = (h2 >= 0) && (h2 < NH) && (w2 >= 0) && (w2 < NW);
      d[dy * 3 + dx] = ok ? drow[h2 * NW + w2] : 0.f;
    }

  // 72 mask values, every load coalesced across lanes (consecutive w)
  const float* mb = mask + (size_t)b * 576 * hw + (size_t)h * NW + w;
  float m[9][FAC];
#pragma unroll
  for (int j = 0; j < 9; ++j)
#pragma unroll
    for (int fx = 0; fx < FAC; ++fx)
      m[j][fx] = mb[(size_t)((j * 8 + fy) * 8 + fx) * hw];

  float o[FAC];
#pragma unroll
  for (int fx = 0; fx < FAC; ++fx) {
    float mx = m[0][fx];
#pragma unroll
    for (int j = 1; j < 9; ++j) mx = fmaxf(mx, m[j][fx]);
    float ssum = 0.f, accv = 0.f;
#pragma unroll
    for (int j = 0; j < 9; ++j) {
      float e = exp2f((m[j][fx] - mx) * sc);
      ssum += e;
      accv += e * d[j];
    }
    o[fx] = -8.0f * accv / ssum;
  }

  float* op = out + ((size_t)b * (NH * FAC) + (size_t)(h * FAC + fy)) * (NW * FAC) + (size_t)w * FAC;
  *reinterpret_cast<float4*>(op)     = float4{o[0], o[1], o[2], o[3]};
  *reinterpret_cast<float4*>(op + 4) = float4{o[4], o[5], o[6], o[7]};
}

extern "C" void kernel_launch(void* const* d_in, const int* in_sizes, int n_in,
                              void* d_out, int out_size, void* d_ws, size_t ws_size,
                              hipStream_t stream) {
  (void)in_sizes; (void)n_in; (void)out_size; (void)ws_size;
  const float* left  = (const float*)d_in[0];
  const float* right = (const float*)d_in[1];
  const float* mask  = (const float*)d_in[2];
  const int*   iters = (const int*)d_in[3];
  float* out  = (float*)d_out;
  float* disp = (float*)d_ws;   // 8*80*160 f32 scratch

  hipLaunchKernelGGL(cost_topk_kernel, dim3(NBATCH * NH), dim3(TPB), 0, stream,
                     left, right, disp);
  hipLaunchKernelGGL(upsample_kernel, dim3(NBATCH * NH * FAC * NW / 256), dim3(256), 0, stream,
                     disp, mask, iters, out);
}

// Round 4
// 147.285 us; speedup vs baseline: 1.8851x; 1.0352x over previous
//
#include <hip/hip_runtime.h>
#include <cmath>

#define NBATCH 8
#define NCH    256
#define NH     80
#define NW     160
#define NDISP  24
#define FAC    8

constexpr int CG   = 8;         // channel groups per block (reduced via shfl butterfly)
constexpr int CPG  = NCH / CG;  // 32 sequential channels per thread
constexpr int WQ   = NW / 4;    // 40 w-quads
constexpr int TPB  = WQ * CG;   // 320 threads = 5 waves
constexpr int ROWF = 348;       // padded floats per staged channel row: 160 L | 24 apron | 160 R | 4 pad
constexpr int BUFF = CG * ROWF; // 2784 floats per stage buffer

// Barrier WITHOUT the compiler's vmcnt(0) drain: LDS visibility only.
// Register-destined global prefetches legally remain in flight across it;
// the compiler inserts counted vmcnt waits at the ds_write that consumes them.
#define BARSYNC() asm volatile("s_waitcnt lgkmcnt(0)\n\ts_barrier" ::: "memory")

__device__ __forceinline__ float f4c(const float4& v, int k) {
  switch (k) { case 0: return v.x; case 1: return v.y; case 2: return v.z; default: return v.w; }
}

// ---------------- K1: cost volume + in-register reduce + top3 + softmax expectation ----------------
// block = one (b,h) row; thread = (cg = t&7, wq = t>>3); 96 accumulators/thread.
__global__ __launch_bounds__(TPB) void cost_topk_kernel(
    const float* __restrict__ left, const float* __restrict__ right,
    float* __restrict__ disp)
{
  __shared__ float smem[2 * BUFF];     // 22272 B

  const int t  = threadIdx.x;
  const int cg = t & 7;
  const int wq = t >> 3;
  const int w0 = wq * 4;
  const int b  = blockIdx.x / NH;
  const int h  = blockIdx.x % NH;

  const size_t hw = (size_t)NH * NW;
  const float* lrow = left  + (size_t)b * NCH * hw + (size_t)h * NW;
  const float* rrow = right + (size_t)b * NCH * hw + (size_t)h * NW;

  // zero the 24-float R aprons of both stage buffers
  for (int q = t; q < 2 * CG * 6; q += TPB) {
    int buf = q / 48, ch = (q / 6) % 8, k = q % 6;
    *reinterpret_cast<float4*>(&smem[buf * BUFF + ch * ROWF + 160 + 4 * k]) = float4{0.f, 0.f, 0.f, 0.f};
  }

  // staging: this thread owns global quads qa=t, qb=t+TPB of 640 (8ch x (40 L + 40 R) quads)
  const int qa = t, qb = t + TPB;
  const int chA = qa / 80, remA = qa % 80;
  const int chB = qb / 80, remB = qb % 80;
  const int ldsA = chA * ROWF + ((remA < 40) ? remA * 4 : 184 + (remA - 40) * 4);
  const int ldsB = chB * ROWF + ((remB < 40) ? remB * 4 : 184 + (remB - 40) * 4);
  const float* gA = ((remA < 40) ? lrow : rrow) + (size_t)chA * CPG * hw + ((remA < 40) ? remA * 4 : (remA - 40) * 4);
  const float* gB = ((remB < 40) ? lrow : rrow) + (size_t)chB * CPG * hw + ((remB < 40) ? remB * 4 : (remB - 40) * 4);

  float acc[NDISP][4];
#pragma unroll
  for (int i = 0; i < NDISP; ++i)
#pragma unroll
    for (int ws = 0; ws < 4; ++ws) acc[i][ws] = 0.f;

  // depth-2 register prefetch: set A holds even-j data, set B odd-j data
  float4 sA0 = *reinterpret_cast<const float4*>(gA);
  float4 sA1 = *reinterpret_cast<const float4*>(gB);
  float4 sB0 = *reinterpret_cast<const float4*>(gA + hw);
  float4 sB1 = *reinterpret_cast<const float4*>(gB + hw);

  auto compute = [&](const float* base) {
    const float* row = base + cg * ROWF;             // this thread's channel row
    float4 L  = *reinterpret_cast<const float4*>(row + w0);
    float4 Qa = *reinterpret_cast<const float4*>(row + 160 + w0);        // R[x=w0-24..w0-21]
#pragma unroll
    for (int g = 0; g < 6; ++g) {
      const int i0 = 20 - 4 * g;
      float4 Qb = *reinterpret_cast<const float4*>(row + 184 + w0 - i0); // R[x=w0-i0..]
#pragma unroll
      for (int di = 0; di < 4; ++di)
#pragma unroll
        for (int ws = 0; ws < 4; ++ws) {
          const int pos = ws - di + 4;               // 1..7 within [Qa|Qb]
          float rv = (pos < 4) ? f4c(Qa, pos) : f4c(Qb, pos - 4);
          acc[i0 + di][ws] = __builtin_fmaf(f4c(L, ws), rv, acc[i0 + di][ws]);
        }
      Qa = Qb;
    }
  };

  for (int jj = 0; jj < CPG; jj += 2) {
    // ---- even step: buffer 0, set A ----
    BARSYNC();                                       // prior compute on buffer 0 done
    *reinterpret_cast<float4*>(&smem[ldsA]) = sA0;   // hw inserts counted vmcnt wait here
    *reinterpret_cast<float4*>(&smem[ldsB]) = sA1;
    if (jj + 2 < CPG) {                              // issue loads for step jj+2 (in flight across 2 barriers)
      sA0 = *reinterpret_cast<const float4*>(gA + (size_t)(jj + 2) * hw);
      sA1 = *reinterpret_cast<const float4*>(gB + (size_t)(jj + 2) * hw);
    }
    BARSYNC();                                       // writes visible
    compute(&smem[0]);
    // ---- odd step: buffer 1, set B ----
    BARSYNC();
    *reinterpret_cast<float4*>(&smem[BUFF + ldsA]) = sB0;
    *reinterpret_cast<float4*>(&smem[BUFF + ldsB]) = sB1;
    if (jj + 3 < CPG) {
      sB0 = *reinterpret_cast<const float4*>(gA + (size_t)(jj + 3) * hw);
      sB1 = *reinterpret_cast<const float4*>(gB + (size_t)(jj + 3) * hw);
    }
    BARSYNC();
    compute(&smem[BUFF]);
  }

  // -------- butterfly reduce over the 8 cg lanes (deterministic symmetric tree) --------
#pragma unroll
  for (int mskm = 1; mskm < 8; mskm <<= 1)
#pragma unroll
    for (int i = 0; i < NDISP; ++i)
#pragma unroll
      for (int ws = 0; ws < 4; ++ws)
        acc[i][ws] += __shfl_xor(acc[i][ws], mskm, 64);

  if (cg == 0) {
    float o[4];
#pragma unroll
    for (int ws = 0; ws < 4; ++ws) {
      float v1 = -1e30f, v2 = -1e30f, v3 = -1e30f;
      int   j1 = 0, j2 = 0, j3 = 0;
#pragma unroll
      for (int i = 0; i < NDISP; ++i) {
        float v = acc[i][ws] * 0.00390625f;          // mean: exact *2^-8
        if (v > v1)      { v3 = v2; j3 = j2; v2 = v1; j2 = j1; v1 = v; j1 = i; }
        else if (v > v2) { v3 = v2; j3 = j2; v2 = v;  j2 = i; }
        else if (v > v3) { v3 = v;  j3 = i; }
      }
      float e2 = expf(v2 - v1), e3 = expf(v3 - v1);
      float ssum = 1.0f + e2 + e3;
      o[ws] = ((float)j1 + e2 * (float)j2 + e3 * (float)j3) / ssum;
    }
    *reinterpret_cast<float4*>(&disp[((size_t)b * NH + h) * NW + w0]) = float4{o[0], o[1], o[2], o[3]};
  }
}

// ---------------- K2: convex upsample, one thread per (b,h,fy,w) -> 8 fx outputs ----------------
__global__ __launch_bounds__(256) void upsample_kernel(
    const float* __restrict__ disp, const float* __restrict__ mask,
    const int* __restrict__ itp, float* __restrict__ out)
{
  int idx = blockIdx.x * 256 + threadIdx.x;          // 8*80*8*160 = 819,200 exactly
  const int w  = idx % NW;
  const int fy = (idx / NW) & 7;
  const int h  = (idx / (NW * FAC)) % NH;
  const int b  = idx / (NW * FAC * NH);

  const float iters = (float)itp[0];
  const float temp  = 1.0f + __expf(-(iters - 1.0f));
  const float sc    = 1.44269504088896340736f / temp;  // log2(e)/temp

  const size_t hw = (size_t)NH * NW;
  const float* drow = disp + (size_t)b * hw;
  float d[9];
#pragma unroll
  for (int dy = 0; dy < 3; ++dy)
#pragma unroll
    for (int dx = 0; dx < 3; ++dx) {
      int h2 = h + dy - 1, w2 = w + dx - 1;
      bool ok = (h2 >= 0) && (h2 < NH) && (w2 >= 0) && (w2 < NW);
      d[dy * 3 + dx] = ok ? drow[h2 * NW + w2] : 0.f;
    }

  // 72 mask values, every load coalesced across lanes (consecutive w)
  const float* mb = mask + (size_t)b * 576 * hw + (size_t)h * NW + w;
  float m[9][FAC];
#pragma unroll
  for (int j = 0; j < 9; ++j)
#pragma unroll
    for (int fx = 0; fx < FAC; ++fx)
      m[j][fx] = mb[(size_t)((j * 8 + fy) * 8 + fx) * hw];

  float o[FAC];
#pragma unroll
  for (int fx = 0; fx < FAC; ++fx) {
    float mx = m[0][fx];
#pragma unroll
    for (int j = 1; j < 9; ++j) mx = fmaxf(mx, m[j][fx]);
    float ssum = 0.f, accv = 0.f;
#pragma unroll
    for (int j = 0; j < 9; ++j) {
      float e = exp2f((m[j][fx] - mx) * sc);
      ssum += e;
      accv += e * d[j];
    }
    o[fx] = (-8.0f * accv) * __builtin_amdgcn_rcpf(ssum);
  }

  float* op = out + ((size_t)b * (NH * FAC) + (size_t)(h * FAC + fy)) * (NW * FAC) + (size_t)w * FAC;
  *reinterpret_cast<float4*>(op)     = float4{o[0], o[1], o[2], o[3]};
  *reinterpret_cast<float4*>(op + 4) = float4{o[4], o[5], o[6], o[7]};
}

extern "C" void kernel_launch(void* const* d_in, const int* in_sizes, int n_in,
                              void* d_out, int out_size, void* d_ws, size_t ws_size,
                              hipStream_t stream) {
  (void)in_sizes; (void)n_in; (void)out_size; (void)ws_size;
  const float* left  = (const float*)d_in[0];
  const float* right = (const float*)d_in[1];
  const float* mask  = (const float*)d_in[2];
  const int*   iters = (const int*)d_in[3];
  float* out  = (float*)d_out;
  float* disp = (float*)d_ws;   // 8*80*160 f32 scratch

  hipLaunchKernelGGL(cost_topk_kernel, dim3(NBATCH * NH), dim3(TPB), 0, stream,
                     left, right, disp);
  hipLaunchKernelGGL(upsample_kernel, dim3(NBATCH * NH * FAC * NW / 256), dim3(256), 0, stream,
                     disp, mask, iters, out);
}